// Round 9
// baseline (255.905 us; speedup 1.0000x reference)
//
#include <hip/hip_runtime.h>
#include <math.h>

// ---------------------------------------------------------------------------
// Problem constants
// ---------------------------------------------------------------------------
#define BATCH 16
#define CH    256          // channels C
#define NT    1024         // tokens n = 32*32
#define NH    8            // heads
#define DH    32           // dim_head
#define HID   1024         // ffn hidden
#define MROWS (BATCH * NT) // 16384 rows for all GEMMs
#define LN_EPS 1e-5f

typedef unsigned short u16;
typedef unsigned int u32;
typedef __attribute__((ext_vector_type(8))) short short8;   // 8 x bf16 (4 VGPRs)
typedef __attribute__((ext_vector_type(4))) short short4v;  // 4 x bf16 (2 VGPRs)
typedef __attribute__((ext_vector_type(4))) float f32x4;

struct __align__(8) US4 { u16 x, y, z, w; };
struct __align__(16) F4 { float x, y, z, w; };

#define MFMA(a, b, c) __builtin_amdgcn_mfma_f32_16x16x32_bf16((a), (b), (c), 0, 0, 0)
// v_mfma_f32_16x16x16_bf16 (gfx90a-lineage "_1k" builtin name); defined
// unconditionally: __has_builtin is false on the HIP *host* pass.
#define MFMA16(a, b, c) __builtin_amdgcn_mfma_f32_16x16x16bf16_1k((a), (b), (c), 0, 0, 0)

#define LOG2E 1.4426950408889634f
#define QSCALE (0.17677669529663687f * 1.4426950408889634f)  // scale * log2e

__device__ __forceinline__ float bf2f(u16 u) {
  union { unsigned int i; float f; } v; v.i = ((unsigned int)u) << 16; return v.f;
}
__device__ __forceinline__ u16 f2bf(float f) {
  union { float f; unsigned int i; } v; v.f = f;
  unsigned int i = v.i;
  return (u16)((i + 0x7fffu + ((i >> 16) & 1u)) >> 16);  // RNE
}
__device__ __forceinline__ u32 pack_bf16_pair(float lo, float hi) {
  union { float f; u32 i; } a, b; a.f = lo; b.f = hi;
#if defined(__HIP_DEVICE_COMPILE__)
  return __builtin_amdgcn_perm(b.i, a.i, 0x07060302u);
#else
  return (b.i & 0xFFFF0000u) | (a.i >> 16);
#endif
}
// RAW v_exp_f32 (1 transcendental inst). Round-7 lesson: plain exp2f lowers
// to the libm path (~8-10 VALU) and cost +20 us in k_attn.
__device__ __forceinline__ float fast_exp2(float x) {
#if defined(__HIP_DEVICE_COMPILE__)
  return __builtin_amdgcn_exp2f(x);
#else
  return exp2f(x);
#endif
}
// tanh-form GELU via raw exp2 (|err| <~ 3e-3, tolerance 0.1)
__device__ __forceinline__ float fast_gelu(float x) {
  const float c = 2.0f * LOG2E * 0.7978845608028654f;
  float t = fast_exp2(c * (x + 0.044715f * x * x * x));
  return x * t / (t + 1.0f);
}
// async global->LDS, 16 B per lane; LDS dest = uniform base + lane*16
__device__ __forceinline__ void llds16(const u16* g, u16* l) {
  __builtin_amdgcn_global_load_lds(
      (const __attribute__((address_space(1))) u32*)g,
      (__attribute__((address_space(3))) u32*)l, 16, 0, 0);
}

// ---------------------------------------------------------------------------
// Weight transpose + fp32->bf16: in (K x N) fp32 -> out (N x K) bf16
// ---------------------------------------------------------------------------
__global__ __launch_bounds__(256) void k_transpose(const float* __restrict__ in,
                                                   u16* __restrict__ out,
                                                   int K, int N) {
  __shared__ u16 tl[64][66];
  const int t = threadIdx.x;
  const int kb = blockIdx.x * 64, nb = blockIdx.y * 64;
#pragma unroll
  for (int it = 0; it < 16; ++it) {
    int n_l = t & 63, k_l = it * 4 + (t >> 6);
    tl[k_l][n_l] = f2bf(in[(size_t)(kb + k_l) * N + nb + n_l]);
  }
  __syncthreads();
#pragma unroll
  for (int it = 0; it < 16; ++it) {
    int k_l = t & 63, n_l = it * 4 + (t >> 6);
    out[(size_t)(nb + n_l) * K + kb + k_l] = tl[k_l][n_l];
  }
}

// ---------------------------------------------------------------------------
// Bias pre-gather, scaled by log2e, layout [h][jt][i][j']  (jt=j>>5, j'=j&31)
// grid: 256 (32 jt x 8 i-slices), block 256
// ---------------------------------------------------------------------------
__global__ __launch_bounds__(256) void k_prep_bias(const float* __restrict__ table,
                                                   const int* __restrict__ rel,
                                                   u16* __restrict__ biasL) {
  const int t = threadIdx.x;
  const int jt = blockIdx.x & 31, isl = blockIdx.x >> 5;
  const int jp = t & 31, io = t >> 5;
  for (int ib = isl * 128; ib < isl * 128 + 128; ib += 8) {
    int i = ib + io;
    int idx = rel[(size_t)i * NT + jt * 32 + jp];
#pragma unroll
    for (int h = 0; h < NH; ++h) {
      biasL[(((size_t)h * 32 + jt) * 1024 + i) * 32 + jp] =
          f2bf(table[(size_t)idx * NH + h] * LOG2E);
    }
  }
}

// ---------------------------------------------------------------------------
// LN1 fused with (B,C,n) -> (B,n,C) transpose + fp32->bf16.
// ---------------------------------------------------------------------------
__global__ __launch_bounds__(256) void k_ln1(const float* __restrict__ x,
                                             const float* __restrict__ w,
                                             const float* __restrict__ b,
                                             u16* __restrict__ x1) {
  __shared__ u16 tile[CH][68];
  __shared__ float red_s[4][64], red_q[4][64], mu_s[64], rs_s[64];
  const int t = threadIdx.x;
  const int bb = blockIdx.x >> 4, pb = blockIdx.x & 15;
  const int pos0 = pb * 64;
#pragma unroll
  for (int it = 0; it < 16; ++it) {
    int c = it * 16 + (t >> 4), p4 = (t & 15) * 4;
    F4 v = *(const F4*)(x + ((size_t)bb * CH + c) * NT + pos0 + p4);
    US4 o; o.x = f2bf(v.x); o.y = f2bf(v.y); o.z = f2bf(v.z); o.w = f2bf(v.w);
    *(US4*)&tile[c][p4] = o;
  }
  __syncthreads();
  {
    int pos = t & 63, g = t >> 6;
    float s = 0.f, q = 0.f;
#pragma unroll 8
    for (int cc = 0; cc < 64; ++cc) {
      float v = bf2f(tile[g * 64 + cc][pos]);
      s += v; q += v * v;
    }
    red_s[g][pos] = s; red_q[g][pos] = q;
  }
  __syncthreads();
  if (t < 64) {
    float s = red_s[0][t] + red_s[1][t] + red_s[2][t] + red_s[3][t];
    float q = red_q[0][t] + red_q[1][t] + red_q[2][t] + red_q[3][t];
    float mu = s * (1.f / CH);
    float var = q * (1.f / CH) - mu * mu;
    mu_s[t] = mu;
    rs_s[t] = rsqrtf(fmaxf(var, 0.f) + LN_EPS);
  }
  __syncthreads();
  {
    const int c = t;
    const float wv = w[c], bv = b[c];
    for (int pos = 0; pos < 64; ++pos) {
      float v = (bf2f(tile[c][pos]) - mu_s[pos]) * rs_s[pos] * wv + bv;
      x1[((size_t)bb * NT + pos0 + pos) * CH + c] = f2bf(v);
    }
  }
}

// ---------------------------------------------------------------------------
// m97-style LDS-staged GEMM core: 128x128 block tile, BK=32, 4 waves x 64x64.
// ---------------------------------------------------------------------------
template <int K>
__device__ __forceinline__ void gemm128(const u16* __restrict__ A,
                                        const u16* __restrict__ Bt,
                                        int r0, int c0, int tid,
                                        u16* lA, u16* lB,
                                        f32x4 acc[4][4]) {
  const int wave = tid >> 6, lane = tid & 63;
  const int wm = (wave >> 1) * 64, wn = (wave & 1) * 64;
  const int l16 = lane & 15, quad = lane >> 4;
  const int srow = lane >> 2;
  const int scol = (lane & 3) * 8;
  const u16* gA0 = A + (size_t)(r0 + wave * 16 + srow) * K + scol;
  const u16* gA1 = A + (size_t)(r0 + wave * 16 + 64 + srow) * K + scol;
  const u16* gB0 = Bt + (size_t)(c0 + wave * 16 + srow) * K + scol;
  const u16* gB1 = Bt + (size_t)(c0 + wave * 16 + 64 + srow) * K + scol;
  u16* lA0 = lA + (wave * 16) * 32;
  u16* lA1 = lA + (wave * 16 + 64) * 32;
  u16* lB0 = lB + (wave * 16) * 32;
  u16* lB1 = lB + (wave * 16 + 64) * 32;
  for (int k0 = 0; k0 < K; k0 += 32) {
    __syncthreads();
    llds16(gA0 + k0, lA0);
    llds16(gA1 + k0, lA1);
    llds16(gB0 + k0, lB0);
    llds16(gB1 + k0, lB1);
    __syncthreads();
    short8 af[4], bf[4];
#pragma unroll
    for (int i = 0; i < 4; ++i)
      af[i] = *(const short8*)&lA[(wm + i * 16 + l16) * 32 + quad * 8];
#pragma unroll
    for (int j = 0; j < 4; ++j)
      bf[j] = *(const short8*)&lB[(wn + j * 16 + l16) * 32 + quad * 8];
#pragma unroll
    for (int i = 0; i < 4; ++i)
#pragma unroll
      for (int j = 0; j < 4; ++j)
        acc[i][j] = MFMA(af[i], bf[j], acc[i][j]);
  }
}

#define GEMM_PROLOGUE(KVAL, APTR, BPTR)                                  \
  __shared__ __align__(16) u16 lA[128 * 32];                             \
  __shared__ __align__(16) u16 lB[128 * 32];                             \
  const int tid = threadIdx.x;                                           \
  const int wave = tid >> 6, lane = tid & 63;                            \
  const int wm = (wave >> 1) * 64, wn = (wave & 1) * 64;                 \
  const int l16 = lane & 15, quad = lane >> 4;                           \
  const int r0 = blockIdx.x * 128, c0 = blockIdx.y * 128;                \
  f32x4 acc[4][4];                                                       \
  _Pragma("unroll") for (int i = 0; i < 4; ++i)                          \
  _Pragma("unroll") for (int j = 0; j < 4; ++j) acc[i][j] = 0.f;         \
  gemm128<KVAL>(APTR, BPTR, r0, c0, tid, lA, lB, acc);

// QKV: x1(16384x256) @ qkv_wT(768x256)^T -> q (scaled), k, vT (B,H,d,n)
__global__ __launch_bounds__(256) void k_gemm_qkv(const u16* __restrict__ x1,
                                                  const u16* __restrict__ wT,
                                                  u16* __restrict__ q,
                                                  u16* __restrict__ k,
                                                  u16* __restrict__ vT) {
  GEMM_PROLOGUE(CH, x1, wT)
#pragma unroll
  for (int j = 0; j < 4; ++j) {
    int col = c0 + wn + j * 16 + l16;
    int which = col >> 8, rem = col & 255, h = rem >> 5, dd = rem & 31;
#pragma unroll
    for (int i = 0; i < 4; ++i) {
      int row0 = r0 + wm + i * 16 + quad * 4;
      int bb = row0 >> 10, pos = row0 & 1023;
      if (which == 2) {
        US4 o;
        o.x = f2bf(acc[i][j][0]); o.y = f2bf(acc[i][j][1]);
        o.z = f2bf(acc[i][j][2]); o.w = f2bf(acc[i][j][3]);
        *(US4*)(vT + (((size_t)bb * NH + h) * DH + dd) * NT + pos) = o;
      } else {
        u16* dst = (which == 0) ? q : k;
        float mul = (which == 0) ? QSCALE : 1.0f;
#pragma unroll
        for (int r = 0; r < 4; ++r)
          dst[(((size_t)bb * NH + h) * NT + pos + r) * DH + dd] =
              f2bf(acc[i][j][r] * mul);
      }
    }
  }
}

// PROJ: attn_out(16384x256) @ proj_wT + proj_b + x^T -> x3 (B,n,C) bf16
__global__ __launch_bounds__(256) void k_gemm_proj(const u16* __restrict__ ao,
                                                   const u16* __restrict__ wT,
                                                   const float* __restrict__ pb,
                                                   const float* __restrict__ x,
                                                   u16* __restrict__ x3) {
  GEMM_PROLOGUE(CH, ao, wT)
#pragma unroll
  for (int j = 0; j < 4; ++j) {
    int col = c0 + wn + j * 16 + l16;
    float bias = pb[col];
#pragma unroll
    for (int i = 0; i < 4; ++i) {
      int row0 = r0 + wm + i * 16 + quad * 4;
      int bb = row0 >> 10, pos = row0 & 1023;
#pragma unroll
      for (int r = 0; r < 4; ++r) {
        float val = acc[i][j][r] + bias + x[((size_t)bb * CH + col) * NT + pos + r];
        x3[(size_t)(row0 + r) * CH + col] = f2bf(val);
      }
    }
  }
}

// FFN1: x4ln(16384x256) @ w1T + b1, fast GELU -> ffn_h (16384x1024) bf16
__global__ __launch_bounds__(256) void k_gemm_ffn1(const u16* __restrict__ a,
                                                   const u16* __restrict__ wT,
                                                   const float* __restrict__ b1,
                                                   u16* __restrict__ hmat) {
  GEMM_PROLOGUE(CH, a, wT)
#pragma unroll
  for (int j = 0; j < 4; ++j) {
    int col = c0 + wn + j * 16 + l16;
    float bias = b1[col];
#pragma unroll
    for (int i = 0; i < 4; ++i) {
      int row0 = r0 + wm + i * 16 + quad * 4;
#pragma unroll
      for (int r = 0; r < 4; ++r) {
        float v = acc[i][j][r] + bias;
        hmat[(size_t)(row0 + r) * HID + col] = f2bf(fast_gelu(v));
      }
    }
  }
}

// FFN2 (+ fused final residual & transpose): ffn_h @ w2T + b2, then
// out[b][col][pos] = x4 + x3[b][pos][col]  (fp32 out, replaces k_add_t)
__global__ __launch_bounds__(256) void k_gemm_ffn2(const u16* __restrict__ a,
                                                   const u16* __restrict__ wT,
                                                   const float* __restrict__ b2,
                                                   const u16* __restrict__ x3,
                                                   float* __restrict__ out) {
  GEMM_PROLOGUE(HID, a, wT)
#pragma unroll
  for (int j = 0; j < 4; ++j) {
    int col = c0 + wn + j * 16 + l16;
    float bias = b2[j * 16 + l16 + c0 + wn];
#pragma unroll
    for (int i = 0; i < 4; ++i) {
      int row0 = r0 + wm + i * 16 + quad * 4;
      int bb = row0 >> 10, pos = row0 & 1023;
      F4 o;
      float* po = &o.x;
#pragma unroll
      for (int r = 0; r < 4; ++r)
        po[r] = acc[i][j][r] + bias + bf2f(x3[(size_t)(row0 + r) * CH + col]);
      *(F4*)(out + ((size_t)bb * CH + col) * NT + pos) = o;
    }
  }
}

// ---------------------------------------------------------------------------
// Flash attention v3: 128 q-rows/block (2 q-groups per wave).
// S^T = K.Q^T; P lands per-lane as the MFMA16 A-fragment -> PV with NO LDS
// round-trip. K-frags and V-frags are loaded from LDS ONCE and shared by both
// q-groups (halves LDS reads/score); K/V staged once per 128 q (halves
// staging vs 64 q/block). Fixed-max softmax, raw v_exp_f32, full j-unroll.
// grid: 1024, block 256. LDS 37.4 KB -> 4 blocks/CU.
// ---------------------------------------------------------------------------
__global__ __launch_bounds__(256) void k_attn(const u16* __restrict__ q,
                                              const u16* __restrict__ k,
                                              const u16* __restrict__ vT,
                                              const u16* __restrict__ biasL,
                                              u16* __restrict__ ao) {
  __shared__ u16 Ks[256][40];   // [j][d], stride 80 B
  __shared__ u16 Vt[32][264];   // [d][j], stride 528 B
  const int tid = threadIdx.x;
  const int wave = tid >> 6, lane = tid & 63;
  const int quad = lane >> 4, l16 = lane & 15;
  const int bh = blockIdx.x >> 3, qt = blockIdx.x & 7;
  const int h = bh & 7, bb = bh >> 3;
  const int i0 = qt * 128 + wave * 16;   // group g adds g*64

  short8 aq[2];
  const u16* bias_base[2];
  float l_loc[2] = {0.f, 0.f};
  f32x4 accd0[2], accd1[2];
#pragma unroll
  for (int g = 0; g < 2; ++g) {
    aq[g] = *(const short8*)(q + ((size_t)bh * NT + i0 + g * 64 + l16) * DH + quad * 8);
    bias_base[g] =
        biasL + (((size_t)h * 32) * 1024 + (i0 + g * 64 + l16)) * 32 + quad * 4;
    accd0[g] = 0.f; accd1[g] = 0.f;
  }

  for (int chunk = 0; chunk < 4; ++chunk) {
    __syncthreads();
    const int rbase = chunk * 256;
    {
      const int srow = tid >> 3, sdd = (tid & 7) * 4;
#pragma unroll
      for (int it = 0; it < 8; ++it) {
        int rl = it * 32 + srow;
        US4 kv = *(const US4*)(k + ((size_t)bh * NT + rbase + rl) * DH + sdd);
        *(US4*)&Ks[rl][sdd] = kv;
      }
      const int j4 = (tid & 63) * 4;
#pragma unroll
      for (int it = 0; it < 8; ++it) {
        int d = it * 4 + wave;
        US4 vv = *(const US4*)(vT + ((size_t)bh * DH + d) * NT + rbase + j4);
        *(US4*)&Vt[d][j4] = vv;
      }
    }
    __syncthreads();

#pragma unroll
    for (int j0 = 0; j0 < 256; j0 += 32) {
      const int jt = (rbase + j0) >> 5;
      // shared fragments (used by BOTH q-groups)
      short8 ak0 = *(const short8*)&Ks[j0 + l16][quad * 8];
      short8 ak1 = *(const short8*)&Ks[j0 + 16 + l16][quad * 8];
      short4v vb00 = *(const short4v*)&Vt[l16][j0 + quad * 4];
      short4v vb10 = *(const short4v*)&Vt[l16][j0 + 16 + quad * 4];
      short4v vb01 = *(const short4v*)&Vt[16 + l16][j0 + quad * 4];
      short4v vb11 = *(const short4v*)&Vt[16 + l16][j0 + 16 + quad * 4];
#pragma unroll
      for (int g = 0; g < 2; ++g) {
        const u16* bl = bias_base[g] + (size_t)jt * 32768;
        US4 b0 = *(const US4*)bl;
        US4 b1 = *(const US4*)(bl + 16);
        f32x4 cc0, cc1;
        cc0[0] = bf2f(b0.x); cc0[1] = bf2f(b0.y);
        cc0[2] = bf2f(b0.z); cc0[3] = bf2f(b0.w);
        cc1[0] = bf2f(b1.x); cc1[1] = bf2f(b1.y);
        cc1[2] = bf2f(b1.z); cc1[3] = bf2f(b1.w);
        f32x4 s0 = MFMA(ak0, aq[g], cc0);  // S^T[j=quad*4+r][q=l16]
        f32x4 s1 = MFMA(ak1, aq[g], cc1);
        float p00 = fast_exp2(s0[0]), p01 = fast_exp2(s0[1]);
        float p02 = fast_exp2(s0[2]), p03 = fast_exp2(s0[3]);
        float p10 = fast_exp2(s1[0]), p11 = fast_exp2(s1[1]);
        float p12 = fast_exp2(s1[2]), p13 = fast_exp2(s1[3]);
        l_loc[g] += ((p00 + p01) + (p02 + p03)) + ((p10 + p11) + (p12 + p13));
        union { u32 u[2]; short4v s; } pa0, pa1;
        pa0.u[0] = pack_bf16_pair(p00, p01);
        pa0.u[1] = pack_bf16_pair(p02, p03);
        pa1.u[0] = pack_bf16_pair(p10, p11);
        pa1.u[1] = pack_bf16_pair(p12, p13);
        accd0[g] = MFMA16(pa0.s, vb00, accd0[g]);
        accd1[g] = MFMA16(pa0.s, vb01, accd1[g]);
        accd0[g] = MFMA16(pa1.s, vb10, accd0[g]);
        accd1[g] = MFMA16(pa1.s, vb11, accd1[g]);
      }
    }
  }
#pragma unroll
  for (int g = 0; g < 2; ++g) {
    float ll = l_loc[g];
    ll += __shfl_xor(ll, 16);
    ll += __shfl_xor(ll, 32);
#pragma unroll
    for (int r = 0; r < 4; ++r) {
      float lr = __shfl(ll, quad * 4 + r);  // l for q = quad*4+r
      float inv = 1.0f / lr;
      int row = i0 + g * 64 + quad * 4 + r;
      u16* o = ao + ((size_t)bb * NT + row) * CH + h * DH;
      o[l16]      = f2bf(accd0[g][r] * inv);
      o[16 + l16] = f2bf(accd1[g][r] * inv);
    }
  }
}

// ---------------------------------------------------------------------------
// LN2: x3 (B,n,C) bf16 rows contiguous -> x4ln (B,n,C) bf16. One wave per row.
// ---------------------------------------------------------------------------
__global__ __launch_bounds__(256) void k_ln2(const u16* __restrict__ x3,
                                             const float* __restrict__ w,
                                             const float* __restrict__ b,
                                             u16* __restrict__ x4ln) {
  const int wave = threadIdx.x >> 6, lane = threadIdx.x & 63;
  const size_t row = (size_t)blockIdx.x * 4 + wave;
  US4 u = *(const US4*)(x3 + row * CH + lane * 4);
  float v0 = bf2f(u.x), v1 = bf2f(u.y), v2 = bf2f(u.z), v3 = bf2f(u.w);
  float s = v0 + v1 + v2 + v3;
  float qq = v0 * v0 + v1 * v1 + v2 * v2 + v3 * v3;
#pragma unroll
  for (int mask = 1; mask <= 32; mask <<= 1) {
    s += __shfl_xor(s, mask);
    qq += __shfl_xor(qq, mask);
  }
  float mu = s * (1.f / CH);
  float var = qq * (1.f / CH) - mu * mu;
  float rs = rsqrtf(fmaxf(var, 0.f) + LN_EPS);
  F4 uw = *(const F4*)(w + lane * 4);
  F4 ub = *(const F4*)(b + lane * 4);
  US4 o;
  o.x = f2bf((v0 - mu) * rs * uw.x + ub.x);
  o.y = f2bf((v1 - mu) * rs * uw.y + ub.y);
  o.z = f2bf((v2 - mu) * rs * uw.z + ub.z);
  o.w = f2bf((v3 - mu) * rs * uw.w + ub.w);
  *(US4*)(x4ln + row * CH + lane * 4) = o;
}

// ---------------------------------------------------------------------------
// Launch
// ---------------------------------------------------------------------------
extern "C" void kernel_launch(void* const* d_in, const int* in_sizes, int n_in,
                              void* d_out, int out_size, void* d_ws, size_t ws_size,
                              hipStream_t stream) {
  const float* x       = (const float*)d_in[0];
  const float* qkv_w   = (const float*)d_in[1];
  const float* proj_w  = (const float*)d_in[2];
  const float* proj_b  = (const float*)d_in[3];
  const float* ffn_w1  = (const float*)d_in[4];
  const float* ffn_b1  = (const float*)d_in[5];
  const float* ffn_w2  = (const float*)d_in[6];
  const float* ffn_b2  = (const float*)d_in[7];
  const float* norm1_w = (const float*)d_in[8];
  const float* norm1_b = (const float*)d_in[9];
  const float* norm2_w = (const float*)d_in[10];
  const float* norm2_b = (const float*)d_in[11];
  const float* btab    = (const float*)d_in[12];
  const int* rel       = (const int*)d_in[13];
  float* out = (float*)d_out;

  char* ws = (char*)d_ws;
  size_t off = 0;
  auto alloc = [&](size_t bytes) { char* p = ws + off; off += bytes; return p; };
  u16* qkv_wT  = (u16*)alloc((size_t)768 * 256 * 2);
  u16* proj_wT = (u16*)alloc((size_t)256 * 256 * 2);
  u16* w1T     = (u16*)alloc((size_t)1024 * 256 * 2);
  u16* w2T     = (u16*)alloc((size_t)256 * 1024 * 2);
  u16* biasL   = (u16*)alloc((size_t)NH * NT * NT * 2);   // 16.78 MB
  u16* qm      = (u16*)alloc((size_t)MROWS * CH * 2);     // 8.39 MB
  u16* km      = (u16*)alloc((size_t)MROWS * CH * 2);     // 8.39 MB
  u16* vm      = (u16*)alloc((size_t)MROWS * CH * 2);     // 8.39 MB (as vT)
  u16* bufX    = (u16*)alloc((size_t)MROWS * CH * 2);     // 8.39 MB
  u16* x3      = (u16*)alloc((size_t)MROWS * CH * 2);     // 8.39 MB
  u16* ffn_h = biasL;  // overlay (dead after attention)
  u16* x4ln  = vm;     // overlay (dead after attention)
  u16* x1 = bufX;
  u16* ao = bufX;
  (void)ws_size; (void)in_sizes; (void)n_in; (void)out_size;

  k_transpose<<<dim3(4, 12), 256, 0, stream>>>(qkv_w, qkv_wT, 256, 768);
  k_transpose<<<dim3(4, 4), 256, 0, stream>>>(proj_w, proj_wT, 256, 256);
  k_transpose<<<dim3(4, 16), 256, 0, stream>>>(ffn_w1, w1T, 256, 1024);
  k_transpose<<<dim3(16, 4), 256, 0, stream>>>(ffn_w2, w2T, 1024, 256);
  k_prep_bias<<<256, 256, 0, stream>>>(btab, rel, biasL);
  k_ln1<<<BATCH * 16, 256, 0, stream>>>(x, norm1_w, norm1_b, x1);
  k_gemm_qkv<<<dim3(MROWS / 128, 6), 256, 0, stream>>>(x1, qkv_wT, qm, km, vm);
  k_attn<<<BATCH * NH * 8, 256, 0, stream>>>(qm, km, vm, biasL, ao);
  k_gemm_proj<<<dim3(MROWS / 128, 2), 256, 0, stream>>>(ao, proj_wT, proj_b, x, x3);
  k_ln2<<<MROWS / 4, 256, 0, stream>>>(x3, norm2_w, norm2_b, x4ln);
  k_gemm_ffn1<<<dim3(MROWS / 128, 8), 256, 0, stream>>>(x4ln, w1T, ffn_b1, ffn_h);
  k_gemm_ffn2<<<dim3(MROWS / 128, 2), 256, 0, stream>>>(ffn_h, w2T, ffn_b2, x3, out);
}

// Round 10
// 236.317 us; speedup vs baseline: 1.0829x; 1.0829x over previous
//
#include <hip/hip_runtime.h>
#include <math.h>

// ---------------------------------------------------------------------------
// Problem constants
// ---------------------------------------------------------------------------
#define BATCH 16
#define CH    256          // channels C
#define NT    1024         // tokens n = 32*32
#define NH    8            // heads
#define DH    32           // dim_head
#define HID   1024         // ffn hidden
#define MROWS (BATCH * NT) // 16384 rows for all GEMMs
#define LN_EPS 1e-5f

typedef unsigned short u16;
typedef unsigned int u32;
typedef __attribute__((ext_vector_type(8))) short short8;   // 8 x bf16 (4 VGPRs)
typedef __attribute__((ext_vector_type(4))) short short4v;  // 4 x bf16 (2 VGPRs)
typedef __attribute__((ext_vector_type(4))) float f32x4;

struct __align__(8) US4 { u16 x, y, z, w; };
struct __align__(16) F4 { float x, y, z, w; };

#define MFMA(a, b, c) __builtin_amdgcn_mfma_f32_16x16x32_bf16((a), (b), (c), 0, 0, 0)
// v_mfma_f32_16x16x16_bf16 (gfx90a-lineage "_1k" builtin name); defined
// unconditionally: __has_builtin is false on the HIP *host* pass.
#define MFMA16(a, b, c) __builtin_amdgcn_mfma_f32_16x16x16bf16_1k((a), (b), (c), 0, 0, 0)

#define LOG2E 1.4426950408889634f
#define QSCALE (0.17677669529663687f * 1.4426950408889634f)  // scale * log2e

__device__ __forceinline__ float bf2f(u16 u) {
  union { unsigned int i; float f; } v; v.i = ((unsigned int)u) << 16; return v.f;
}
__device__ __forceinline__ u16 f2bf(float f) {
  union { float f; unsigned int i; } v; v.f = f;
  unsigned int i = v.i;
  return (u16)((i + 0x7fffu + ((i >> 16) & 1u)) >> 16);  // RNE
}
__device__ __forceinline__ u32 pack_bf16_pair(float lo, float hi) {
  union { float f; u32 i; } a, b; a.f = lo; b.f = hi;
#if defined(__HIP_DEVICE_COMPILE__)
  return __builtin_amdgcn_perm(b.i, a.i, 0x07060302u);
#else
  return (b.i & 0xFFFF0000u) | (a.i >> 16);
#endif
}
// RAW v_exp_f32 (1 transcendental inst). Round-7 lesson: plain exp2f lowers
// to the libm path (~8-10 VALU) and cost +20 us in k_attn.
__device__ __forceinline__ float fast_exp2(float x) {
#if defined(__HIP_DEVICE_COMPILE__)
  return __builtin_amdgcn_exp2f(x);
#else
  return exp2f(x);
#endif
}
// tanh-form GELU via raw exp2 (|err| <~ 3e-3, tolerance 0.1)
__device__ __forceinline__ float fast_gelu(float x) {
  const float c = 2.0f * LOG2E * 0.7978845608028654f;
  float t = fast_exp2(c * (x + 0.044715f * x * x * x));
  return x * t / (t + 1.0f);
}
// async global->LDS, 16 B per lane; LDS dest = uniform base + lane*16
__device__ __forceinline__ void llds16(const u16* g, u16* l) {
  __builtin_amdgcn_global_load_lds(
      (const __attribute__((address_space(1))) u32*)g,
      (__attribute__((address_space(3))) u32*)l, 16, 0, 0);
}

// ---------------------------------------------------------------------------
// Weight transpose + fp32->bf16: in (K x N) fp32 -> out (N x K) bf16
// ---------------------------------------------------------------------------
__global__ __launch_bounds__(256) void k_transpose(const float* __restrict__ in,
                                                   u16* __restrict__ out,
                                                   int K, int N) {
  __shared__ u16 tl[64][66];
  const int t = threadIdx.x;
  const int kb = blockIdx.x * 64, nb = blockIdx.y * 64;
#pragma unroll
  for (int it = 0; it < 16; ++it) {
    int n_l = t & 63, k_l = it * 4 + (t >> 6);
    tl[k_l][n_l] = f2bf(in[(size_t)(kb + k_l) * N + nb + n_l]);
  }
  __syncthreads();
#pragma unroll
  for (int it = 0; it < 16; ++it) {
    int k_l = t & 63, n_l = it * 4 + (t >> 6);
    out[(size_t)(nb + n_l) * K + kb + k_l] = tl[k_l][n_l];
  }
}

// ---------------------------------------------------------------------------
// Bias pre-gather, scaled by log2e, b128-packed layout:
//   biasP[h][jt][i][slot], slot(j') = ((j'>>2)&3)*8 + (j'>>4)*4 + (j'&3)
// -> a lane's 8 C-operand values (j' = quad*4+off and 16+quad*4+off) are the
//    contiguous 8 u16 at slot quad*8 -> ONE b128 load per tile in k_attn.
// grid: 256 (32 jt x 8 i-slices), block 256
// ---------------------------------------------------------------------------
__global__ __launch_bounds__(256) void k_prep_bias(const float* __restrict__ table,
                                                   const int* __restrict__ rel,
                                                   u16* __restrict__ biasP) {
  const int t = threadIdx.x;
  const int jt = blockIdx.x & 31, isl = blockIdx.x >> 5;
  const int jp = t & 31, io = t >> 5;
  const int slot = ((jp >> 2) & 3) * 8 + (jp >> 4) * 4 + (jp & 3);
  for (int ib = isl * 128; ib < isl * 128 + 128; ib += 8) {
    int i = ib + io;
    int idx = rel[(size_t)i * NT + jt * 32 + jp];
#pragma unroll
    for (int h = 0; h < NH; ++h) {
      biasP[(((size_t)h * 32 + jt) * 1024 + i) * 32 + slot] =
          f2bf(table[(size_t)idx * NH + h] * LOG2E);
    }
  }
}

// ---------------------------------------------------------------------------
// LN1 fused with (B,C,n) -> (B,n,C) transpose + fp32->bf16.
// ---------------------------------------------------------------------------
__global__ __launch_bounds__(256) void k_ln1(const float* __restrict__ x,
                                             const float* __restrict__ w,
                                             const float* __restrict__ b,
                                             u16* __restrict__ x1) {
  __shared__ u16 tile[CH][68];
  __shared__ float red_s[4][64], red_q[4][64], mu_s[64], rs_s[64];
  const int t = threadIdx.x;
  const int bb = blockIdx.x >> 4, pb = blockIdx.x & 15;
  const int pos0 = pb * 64;
#pragma unroll
  for (int it = 0; it < 16; ++it) {
    int c = it * 16 + (t >> 4), p4 = (t & 15) * 4;
    F4 v = *(const F4*)(x + ((size_t)bb * CH + c) * NT + pos0 + p4);
    US4 o; o.x = f2bf(v.x); o.y = f2bf(v.y); o.z = f2bf(v.z); o.w = f2bf(v.w);
    *(US4*)&tile[c][p4] = o;
  }
  __syncthreads();
  {
    int pos = t & 63, g = t >> 6;
    float s = 0.f, q = 0.f;
#pragma unroll 8
    for (int cc = 0; cc < 64; ++cc) {
      float v = bf2f(tile[g * 64 + cc][pos]);
      s += v; q += v * v;
    }
    red_s[g][pos] = s; red_q[g][pos] = q;
  }
  __syncthreads();
  if (t < 64) {
    float s = red_s[0][t] + red_s[1][t] + red_s[2][t] + red_s[3][t];
    float q = red_q[0][t] + red_q[1][t] + red_q[2][t] + red_q[3][t];
    float mu = s * (1.f / CH);
    float var = q * (1.f / CH) - mu * mu;
    mu_s[t] = mu;
    rs_s[t] = rsqrtf(fmaxf(var, 0.f) + LN_EPS);
  }
  __syncthreads();
  {
    const int c = t;
    const float wv = w[c], bv = b[c];
    for (int pos = 0; pos < 64; ++pos) {
      float v = (bf2f(tile[c][pos]) - mu_s[pos]) * rs_s[pos] * wv + bv;
      x1[((size_t)bb * NT + pos0 + pos) * CH + c] = f2bf(v);
    }
  }
}

// ---------------------------------------------------------------------------
// m97-style LDS-staged GEMM core: 128x128 block tile, BK=32, 4 waves x 64x64.
// ---------------------------------------------------------------------------
template <int K>
__device__ __forceinline__ void gemm128(const u16* __restrict__ A,
                                        const u16* __restrict__ Bt,
                                        int r0, int c0, int tid,
                                        u16* lA, u16* lB,
                                        f32x4 acc[4][4]) {
  const int wave = tid >> 6, lane = tid & 63;
  const int wm = (wave >> 1) * 64, wn = (wave & 1) * 64;
  const int l16 = lane & 15, quad = lane >> 4;
  const int srow = lane >> 2;
  const int scol = (lane & 3) * 8;
  const u16* gA0 = A + (size_t)(r0 + wave * 16 + srow) * K + scol;
  const u16* gA1 = A + (size_t)(r0 + wave * 16 + 64 + srow) * K + scol;
  const u16* gB0 = Bt + (size_t)(c0 + wave * 16 + srow) * K + scol;
  const u16* gB1 = Bt + (size_t)(c0 + wave * 16 + 64 + srow) * K + scol;
  u16* lA0 = lA + (wave * 16) * 32;
  u16* lA1 = lA + (wave * 16 + 64) * 32;
  u16* lB0 = lB + (wave * 16) * 32;
  u16* lB1 = lB + (wave * 16 + 64) * 32;
  for (int k0 = 0; k0 < K; k0 += 32) {
    __syncthreads();
    llds16(gA0 + k0, lA0);
    llds16(gA1 + k0, lA1);
    llds16(gB0 + k0, lB0);
    llds16(gB1 + k0, lB1);
    __syncthreads();
    short8 af[4], bf[4];
#pragma unroll
    for (int i = 0; i < 4; ++i)
      af[i] = *(const short8*)&lA[(wm + i * 16 + l16) * 32 + quad * 8];
#pragma unroll
    for (int j = 0; j < 4; ++j)
      bf[j] = *(const short8*)&lB[(wn + j * 16 + l16) * 32 + quad * 8];
#pragma unroll
    for (int i = 0; i < 4; ++i)
#pragma unroll
      for (int j = 0; j < 4; ++j)
        acc[i][j] = MFMA(af[i], bf[j], acc[i][j]);
  }
}

#define GEMM_PROLOGUE(KVAL, APTR, BPTR)                                  \
  __shared__ __align__(16) u16 lA[128 * 32];                             \
  __shared__ __align__(16) u16 lB[128 * 32];                             \
  const int tid = threadIdx.x;                                           \
  const int wave = tid >> 6, lane = tid & 63;                            \
  const int wm = (wave >> 1) * 64, wn = (wave & 1) * 64;                 \
  const int l16 = lane & 15, quad = lane >> 4;                           \
  const int r0 = blockIdx.x * 128, c0 = blockIdx.y * 128;                \
  f32x4 acc[4][4];                                                       \
  _Pragma("unroll") for (int i = 0; i < 4; ++i)                          \
  _Pragma("unroll") for (int j = 0; j < 4; ++j) acc[i][j] = 0.f;         \
  gemm128<KVAL>(APTR, BPTR, r0, c0, tid, lA, lB, acc);

// ---------------------------------------------------------------------------
// 128x64-tile GEMM core (acc[2][4], LDS 12.3 KB -> ~5 blocks/CU). For the
// N=256 GEMMs (proj, ffn2) whose 128x128 grids were 1 block/CU (barrier
// drain fully exposed -- m114: overlap needs co-resident blocks).
// 4 waves each cover 32 rows x 64 cols.
// ---------------------------------------------------------------------------
template <int K>
__device__ __forceinline__ void gemm128x64(const u16* __restrict__ A,
                                           const u16* __restrict__ Bt,
                                           int r0, int c0, int tid,
                                           u16* lA, u16* lB,
                                           f32x4 acc[2][4]) {
  const int wave = tid >> 6, lane = tid & 63;
  const int wm = wave * 32;
  const int l16 = lane & 15, quad = lane >> 4;
  const int srow = lane >> 2;
  const int scol = (lane & 3) * 8;
  const u16* gA0 = A + (size_t)(r0 + wm + srow) * K + scol;
  const u16* gA1 = A + (size_t)(r0 + wm + 16 + srow) * K + scol;
  const u16* gB0 = Bt + (size_t)(c0 + wave * 16 + srow) * K + scol;
  u16* lA0 = lA + (size_t)wm * 32;
  u16* lA1 = lA + (size_t)(wm + 16) * 32;
  u16* lB0 = lB + (size_t)(wave * 16) * 32;
  for (int k0 = 0; k0 < K; k0 += 32) {
    __syncthreads();
    llds16(gA0 + k0, lA0);
    llds16(gA1 + k0, lA1);
    llds16(gB0 + k0, lB0);
    __syncthreads();
    short8 af[2], bf[4];
#pragma unroll
    for (int i = 0; i < 2; ++i)
      af[i] = *(const short8*)&lA[(wm + i * 16 + l16) * 32 + quad * 8];
#pragma unroll
    for (int j = 0; j < 4; ++j)
      bf[j] = *(const short8*)&lB[(j * 16 + l16) * 32 + quad * 8];
#pragma unroll
    for (int i = 0; i < 2; ++i)
#pragma unroll
      for (int j = 0; j < 4; ++j)
        acc[i][j] = MFMA(af[i], bf[j], acc[i][j]);
  }
}

#define GEMM_PROLOGUE64(KVAL, APTR, BPTR)                                \
  __shared__ __align__(16) u16 lA[128 * 32];                             \
  __shared__ __align__(16) u16 lB[64 * 32];                              \
  const int tid = threadIdx.x;                                           \
  const int wave = tid >> 6, lane = tid & 63;                            \
  const int wm = wave * 32;                                              \
  const int l16 = lane & 15, quad = lane >> 4;                           \
  const int r0 = blockIdx.x * 128, c0 = blockIdx.y * 64;                 \
  f32x4 acc[2][4];                                                       \
  _Pragma("unroll") for (int i = 0; i < 2; ++i)                          \
  _Pragma("unroll") for (int j = 0; j < 4; ++j) acc[i][j] = 0.f;         \
  gemm128x64<KVAL>(APTR, BPTR, r0, c0, tid, lA, lB, acc);

// QKV: x1(16384x256) @ qkv_wT(768x256)^T -> q (scaled), k, vT (B,H,d,n)
__global__ __launch_bounds__(256) void k_gemm_qkv(const u16* __restrict__ x1,
                                                  const u16* __restrict__ wT,
                                                  u16* __restrict__ q,
                                                  u16* __restrict__ k,
                                                  u16* __restrict__ vT) {
  GEMM_PROLOGUE(CH, x1, wT)
#pragma unroll
  for (int j = 0; j < 4; ++j) {
    int col = c0 + wn + j * 16 + l16;
    int which = col >> 8, rem = col & 255, h = rem >> 5, dd = rem & 31;
#pragma unroll
    for (int i = 0; i < 4; ++i) {
      int row0 = r0 + wm + i * 16 + quad * 4;
      int bb = row0 >> 10, pos = row0 & 1023;
      if (which == 2) {
        US4 o;
        o.x = f2bf(acc[i][j][0]); o.y = f2bf(acc[i][j][1]);
        o.z = f2bf(acc[i][j][2]); o.w = f2bf(acc[i][j][3]);
        *(US4*)(vT + (((size_t)bb * NH + h) * DH + dd) * NT + pos) = o;
      } else {
        u16* dst = (which == 0) ? q : k;
        float mul = (which == 0) ? QSCALE : 1.0f;
#pragma unroll
        for (int r = 0; r < 4; ++r)
          dst[(((size_t)bb * NH + h) * NT + pos + r) * DH + dd] =
              f2bf(acc[i][j][r] * mul);
      }
    }
  }
}

// PROJ (128x64 tiles): ao @ proj_wT + proj_b + x^T -> x3 (B,n,C) bf16
__global__ __launch_bounds__(256) void k_gemm_proj(const u16* __restrict__ ao,
                                                   const u16* __restrict__ wT,
                                                   const float* __restrict__ pb,
                                                   const float* __restrict__ x,
                                                   u16* __restrict__ x3) {
  GEMM_PROLOGUE64(CH, ao, wT)
#pragma unroll
  for (int j = 0; j < 4; ++j) {
    int col = c0 + j * 16 + l16;
    float bias = pb[col];
#pragma unroll
    for (int i = 0; i < 2; ++i) {
      int row0 = r0 + wm + i * 16 + quad * 4;
      int bb = row0 >> 10, pos = row0 & 1023;
#pragma unroll
      for (int r = 0; r < 4; ++r) {
        float val = acc[i][j][r] + bias + x[((size_t)bb * CH + col) * NT + pos + r];
        x3[(size_t)(row0 + r) * CH + col] = f2bf(val);
      }
    }
  }
}

// FFN1: x4ln(16384x256) @ w1T + b1, fast GELU -> ffn_h (16384x1024) bf16
__global__ __launch_bounds__(256) void k_gemm_ffn1(const u16* __restrict__ a,
                                                   const u16* __restrict__ wT,
                                                   const float* __restrict__ b1,
                                                   u16* __restrict__ hmat) {
  GEMM_PROLOGUE(CH, a, wT)
#pragma unroll
  for (int j = 0; j < 4; ++j) {
    int col = c0 + wn + j * 16 + l16;
    float bias = b1[col];
#pragma unroll
    for (int i = 0; i < 4; ++i) {
      int row0 = r0 + wm + i * 16 + quad * 4;
#pragma unroll
      for (int r = 0; r < 4; ++r) {
        float v = acc[i][j][r] + bias;
        hmat[(size_t)(row0 + r) * HID + col] = f2bf(fast_gelu(v));
      }
    }
  }
}

// FFN2 (128x64 tiles, + fused final residual & transpose): ffn_h @ w2T + b2,
// then out[b][col][pos] = x4 + x3[b][pos][col]  (fp32 out)
__global__ __launch_bounds__(256) void k_gemm_ffn2(const u16* __restrict__ a,
                                                   const u16* __restrict__ wT,
                                                   const float* __restrict__ b2,
                                                   const u16* __restrict__ x3,
                                                   float* __restrict__ out) {
  GEMM_PROLOGUE64(HID, a, wT)
#pragma unroll
  for (int j = 0; j < 4; ++j) {
    int col = c0 + j * 16 + l16;
    float bias = b2[col];
#pragma unroll
    for (int i = 0; i < 2; ++i) {
      int row0 = r0 + wm + i * 16 + quad * 4;
      int bb = row0 >> 10, pos = row0 & 1023;
      F4 o;
      float* po = &o.x;
#pragma unroll
      for (int r = 0; r < 4; ++r)
        po[r] = acc[i][j][r] + bias + bf2f(x3[(size_t)(row0 + r) * CH + col]);
      *(F4*)(out + ((size_t)bb * CH + col) * NT + pos) = o;
    }
  }
}

// ---------------------------------------------------------------------------
// Flash attention v4 = round-8 structure (64 q/block, measured 60.6 us;
// round-9's 128-q variant regressed to 64.6 -- scheduling loss) + two VALU
// cuts: (1) ONE b128 bias load (packed prep layout) instead of two b64;
// (2) softmax denom l accumulated via MFMA16(P, ones) on the 83%-idle MFMA
// pipe -- D[q=quad*4+r][*] = sum_j P[q][j], exactly the epilogue slot; kills
// 8 v_add/tile and ALL end shuffles. l sums the same truncated-bf16 P as the
// numerator (bias cancels in the ratio).
// grid: 2048, block 256. LDS 37.4 KB -> 4 blocks/CU.
// ---------------------------------------------------------------------------
__global__ __launch_bounds__(256) void k_attn(const u16* __restrict__ q,
                                              const u16* __restrict__ k,
                                              const u16* __restrict__ vT,
                                              const u16* __restrict__ biasP,
                                              u16* __restrict__ ao) {
  __shared__ u16 Ks[256][40];   // [j][d], stride 80 B
  __shared__ u16 Vt[32][264];   // [d][j], stride 528 B
  const int tid = threadIdx.x;
  const int wave = tid >> 6, lane = tid & 63;
  const int quad = lane >> 4, l16 = lane & 15;
  const int bh = blockIdx.x >> 4, qt = blockIdx.x & 15;
  const int h = bh & 7, bb = bh >> 3;
  const int i0 = qt * 64 + wave * 16;

  short8 aq = *(const short8*)(q + ((size_t)bh * NT + i0 + l16) * DH + quad * 8);
  const u16* bias_base =
      biasP + (((size_t)h * 32) * 1024 + (i0 + l16)) * 32 + quad * 8;

  short4v vones;
  vones[0] = vones[1] = vones[2] = vones[3] = (short)0x3F80;  // bf16 1.0
  f32x4 accl = 0.f;                  // l(q=quad*4+r) in every lane
  f32x4 accd0 = 0.f, accd1 = 0.f;    // O[q=quad*4+r][d=l16 / 16+l16]

  for (int chunk = 0; chunk < 4; ++chunk) {
    __syncthreads();
    const int rbase = chunk * 256;
    {
      const int srow = tid >> 3, sdd = (tid & 7) * 4;
#pragma unroll
      for (int it = 0; it < 8; ++it) {
        int rl = it * 32 + srow;
        US4 kv = *(const US4*)(k + ((size_t)bh * NT + rbase + rl) * DH + sdd);
        *(US4*)&Ks[rl][sdd] = kv;
      }
      const int j4 = (tid & 63) * 4;
#pragma unroll
      for (int it = 0; it < 8; ++it) {
        int d = it * 4 + wave;
        US4 vv = *(const US4*)(vT + ((size_t)bh * DH + d) * NT + rbase + j4);
        *(US4*)&Vt[d][j4] = vv;
      }
    }
    __syncthreads();

#pragma unroll 2
    for (int j0 = 0; j0 < 256; j0 += 32) {
      const int jt = (rbase + j0) >> 5;
      // ONE b128: both C-operand halves for this lane
      short8 be = *(const short8*)(bias_base + (size_t)jt * 32768);
      const u16* bep = (const u16*)&be;
      f32x4 cc0, cc1;
#pragma unroll
      for (int r = 0; r < 4; ++r) {
        cc0[r] = bf2f(bep[r]);
        cc1[r] = bf2f(bep[4 + r]);
      }
      short8 ak0 = *(const short8*)&Ks[j0 + l16][quad * 8];
      short8 ak1 = *(const short8*)&Ks[j0 + 16 + l16][quad * 8];
      f32x4 s0 = MFMA(ak0, aq, cc0);  // S^T[j=quad*4+r][q=l16]
      f32x4 s1 = MFMA(ak1, aq, cc1);
      float p00 = fast_exp2(s0[0]), p01 = fast_exp2(s0[1]);
      float p02 = fast_exp2(s0[2]), p03 = fast_exp2(s0[3]);
      float p10 = fast_exp2(s1[0]), p11 = fast_exp2(s1[1]);
      float p12 = fast_exp2(s1[2]), p13 = fast_exp2(s1[3]);
      union { u32 u[2]; short4v s; } pa0, pa1;
      pa0.u[0] = pack_bf16_pair(p00, p01);
      pa0.u[1] = pack_bf16_pair(p02, p03);
      pa1.u[0] = pack_bf16_pair(p10, p11);
      pa1.u[1] = pack_bf16_pair(p12, p13);
      short4v vb00 = *(const short4v*)&Vt[l16][j0 + quad * 4];
      short4v vb10 = *(const short4v*)&Vt[l16][j0 + 16 + quad * 4];
      short4v vb01 = *(const short4v*)&Vt[16 + l16][j0 + quad * 4];
      short4v vb11 = *(const short4v*)&Vt[16 + l16][j0 + 16 + quad * 4];
      accd0 = MFMA16(pa0.s, vb00, accd0);
      accd1 = MFMA16(pa0.s, vb01, accd1);
      accl  = MFMA16(pa0.s, vones, accl);
      accd0 = MFMA16(pa1.s, vb10, accd0);
      accd1 = MFMA16(pa1.s, vb11, accd1);
      accl  = MFMA16(pa1.s, vones, accl);
    }
  }
#pragma unroll
  for (int r = 0; r < 4; ++r) {
    float inv = 1.0f / accl[r];      // l for q = quad*4+r, no shuffles
    int row = i0 + quad * 4 + r;
    u16* o = ao + ((size_t)bb * NT + row) * CH + h * DH;
    o[l16]      = f2bf(accd0[r] * inv);
    o[16 + l16] = f2bf(accd1[r] * inv);
  }
}

// ---------------------------------------------------------------------------
// LN2: x3 (B,n,C) bf16 rows contiguous -> x4ln (B,n,C) bf16. One wave per row.
// ---------------------------------------------------------------------------
__global__ __launch_bounds__(256) void k_ln2(const u16* __restrict__ x3,
                                             const float* __restrict__ w,
                                             const float* __restrict__ b,
                                             u16* __restrict__ x4ln) {
  const int wave = threadIdx.x >> 6, lane = threadIdx.x & 63;
  const size_t row = (size_t)blockIdx.x * 4 + wave;
  US4 u = *(const US4*)(x3 + row * CH + lane * 4);
  float v0 = bf2f(u.x), v1 = bf2f(u.y), v2 = bf2f(u.z), v3 = bf2f(u.w);
  float s = v0 + v1 + v2 + v3;
  float qq = v0 * v0 + v1 * v1 + v2 * v2 + v3 * v3;
#pragma unroll
  for (int mask = 1; mask <= 32; mask <<= 1) {
    s += __shfl_xor(s, mask);
    qq += __shfl_xor(qq, mask);
  }
  float mu = s * (1.f / CH);
  float var = qq * (1.f / CH) - mu * mu;
  float rs = rsqrtf(fmaxf(var, 0.f) + LN_EPS);
  F4 uw = *(const F4*)(w + lane * 4);
  F4 ub = *(const F4*)(b + lane * 4);
  US4 o;
  o.x = f2bf((v0 - mu) * rs * uw.x + ub.x);
  o.y = f2bf((v1 - mu) * rs * uw.y + ub.y);
  o.z = f2bf((v2 - mu) * rs * uw.z + ub.z);
  o.w = f2bf((v3 - mu) * rs * uw.w + ub.w);
  *(US4*)(x4ln + row * CH + lane * 4) = o;
}

// ---------------------------------------------------------------------------
// Launch
// ---------------------------------------------------------------------------
extern "C" void kernel_launch(void* const* d_in, const int* in_sizes, int n_in,
                              void* d_out, int out_size, void* d_ws, size_t ws_size,
                              hipStream_t stream) {
  const float* x       = (const float*)d_in[0];
  const float* qkv_w   = (const float*)d_in[1];
  const float* proj_w  = (const float*)d_in[2];
  const float* proj_b  = (const float*)d_in[3];
  const float* ffn_w1  = (const float*)d_in[4];
  const float* ffn_b1  = (const float*)d_in[5];
  const float* ffn_w2  = (const float*)d_in[6];
  const float* ffn_b2  = (const float*)d_in[7];
  const float* norm1_w = (const float*)d_in[8];
  const float* norm1_b = (const float*)d_in[9];
  const float* norm2_w = (const float*)d_in[10];
  const float* norm2_b = (const float*)d_in[11];
  const float* btab    = (const float*)d_in[12];
  const int* rel       = (const int*)d_in[13];
  float* out = (float*)d_out;

  char* ws = (char*)d_ws;
  size_t off = 0;
  auto alloc = [&](size_t bytes) { char* p = ws + off; off += bytes; return p; };
  u16* qkv_wT  = (u16*)alloc((size_t)768 * 256 * 2);
  u16* proj_wT = (u16*)alloc((size_t)256 * 256 * 2);
  u16* w1T     = (u16*)alloc((size_t)1024 * 256 * 2);
  u16* w2T     = (u16*)alloc((size_t)256 * 1024 * 2);
  u16* biasP   = (u16*)alloc((size_t)NH * NT * NT * 2);   // 16.78 MB
  u16* qm      = (u16*)alloc((size_t)MROWS * CH * 2);     // 8.39 MB
  u16* km      = (u16*)alloc((size_t)MROWS * CH * 2);     // 8.39 MB
  u16* vm      = (u16*)alloc((size_t)MROWS * CH * 2);     // 8.39 MB (as vT)
  u16* bufX    = (u16*)alloc((size_t)MROWS * CH * 2);     // 8.39 MB
  u16* x3      = (u16*)alloc((size_t)MROWS * CH * 2);     // 8.39 MB
  u16* ffn_h = biasP;  // overlay (dead after attention)
  u16* x4ln  = vm;     // overlay (dead after attention)
  u16* x1 = bufX;
  u16* ao = bufX;
  (void)ws_size; (void)in_sizes; (void)n_in; (void)out_size;

  k_transpose<<<dim3(4, 12), 256, 0, stream>>>(qkv_w, qkv_wT, 256, 768);
  k_transpose<<<dim3(4, 4), 256, 0, stream>>>(proj_w, proj_wT, 256, 256);
  k_transpose<<<dim3(4, 16), 256, 0, stream>>>(ffn_w1, w1T, 256, 1024);
  k_transpose<<<dim3(16, 4), 256, 0, stream>>>(ffn_w2, w2T, 1024, 256);
  k_prep_bias<<<256, 256, 0, stream>>>(btab, rel, biasP);
  k_ln1<<<BATCH * 16, 256, 0, stream>>>(x, norm1_w, norm1_b, x1);
  k_gemm_qkv<<<dim3(MROWS / 128, 6), 256, 0, stream>>>(x1, qkv_wT, qm, km, vm);
  k_attn<<<BATCH * NH * 16, 256, 0, stream>>>(qm, km, vm, biasP, ao);
  k_gemm_proj<<<dim3(MROWS / 128, 4), 256, 0, stream>>>(ao, proj_wT, proj_b, x, x3);
  k_ln2<<<MROWS / 4, 256, 0, stream>>>(x3, norm2_w, norm2_b, x4ln);
  k_gemm_ffn1<<<dim3(MROWS / 128, 8), 256, 0, stream>>>(x4ln, w1T, ffn_b1, ffn_h);
  k_gemm_ffn2<<<dim3(MROWS / 128, 4), 256, 0, stream>>>(ffn_h, w2T, ffn_b2, x3, out);
}

// Round 11
// 220.376 us; speedup vs baseline: 1.1612x; 1.0723x over previous
//
#include <hip/hip_runtime.h>
#include <math.h>

// ---------------------------------------------------------------------------
// Problem constants
// ---------------------------------------------------------------------------
#define BATCH 16
#define CH    256          // channels C
#define NT    1024         // tokens n = 32*32
#define NH    8            // heads
#define DH    32           // dim_head
#define HID   1024         // ffn hidden
#define MROWS (BATCH * NT) // 16384 rows for all GEMMs
#define LN_EPS 1e-5f

typedef unsigned short u16;
typedef unsigned int u32;
typedef __attribute__((ext_vector_type(8))) short short8;   // 8 x bf16 (4 VGPRs)
typedef __attribute__((ext_vector_type(4))) short short4v;  // 4 x bf16 (2 VGPRs)
typedef __attribute__((ext_vector_type(4))) float f32x4;

struct __align__(8) US4 { u16 x, y, z, w; };
struct __align__(16) F4 { float x, y, z, w; };

#define MFMA(a, b, c) __builtin_amdgcn_mfma_f32_16x16x32_bf16((a), (b), (c), 0, 0, 0)
// v_mfma_f32_16x16x16_bf16 (gfx90a-lineage "_1k" builtin name); defined
// unconditionally: __has_builtin is false on the HIP *host* pass.
#define MFMA16(a, b, c) __builtin_amdgcn_mfma_f32_16x16x16bf16_1k((a), (b), (c), 0, 0, 0)

#define LOG2E 1.4426950408889634f
#define QSCALE (0.17677669529663687f * 1.4426950408889634f)  // scale * log2e

__device__ __forceinline__ float bf2f(u16 u) {
  union { unsigned int i; float f; } v; v.i = ((unsigned int)u) << 16; return v.f;
}
__device__ __forceinline__ u16 f2bf(float f) {
  union { float f; unsigned int i; } v; v.f = f;
  unsigned int i = v.i;
  return (u16)((i + 0x7fffu + ((i >> 16) & 1u)) >> 16);  // RNE
}
__device__ __forceinline__ u32 pack_bf16_pair(float lo, float hi) {
  union { float f; u32 i; } a, b; a.f = lo; b.f = hi;
#if defined(__HIP_DEVICE_COMPILE__)
  return __builtin_amdgcn_perm(b.i, a.i, 0x07060302u);
#else
  return (b.i & 0xFFFF0000u) | (a.i >> 16);
#endif
}
// RAW v_exp_f32 (1 transcendental inst). Round-7 lesson: plain exp2f lowers
// to the libm path (~8-10 VALU) and cost +20 us in k_attn.
__device__ __forceinline__ float fast_exp2(float x) {
#if defined(__HIP_DEVICE_COMPILE__)
  return __builtin_amdgcn_exp2f(x);
#else
  return exp2f(x);
#endif
}
// tanh-form GELU via raw exp2 (|err| <~ 3e-3, tolerance 0.1)
__device__ __forceinline__ float fast_gelu(float x) {
  const float c = 2.0f * LOG2E * 0.7978845608028654f;
  float t = fast_exp2(c * (x + 0.044715f * x * x * x));
  return x * t / (t + 1.0f);
}
// async global->LDS, 16 B per lane; LDS dest = uniform base + lane*16
__device__ __forceinline__ void llds16(const u16* g, u16* l) {
  __builtin_amdgcn_global_load_lds(
      (const __attribute__((address_space(1))) u32*)g,
      (__attribute__((address_space(3))) u32*)l, 16, 0, 0);
}

// ---------------------------------------------------------------------------
// Fused prep kernel: 4 weight transposes + bias gather + LN1 in ONE dispatch
// (round-11: these 6 kernels are mutually independent; separate dispatches
// serialize on the stream and cost ~2-4 us each in graph-replay gaps).
// Branch on blockIdx.x is block-uniform -> no divergence; bodies identical
// to round-10 versions.
// grid: 704 = 48(qkv_w) + 16(proj_w) + 64(w1) + 64(w2) + 256(bias) + 256(ln1)
// ---------------------------------------------------------------------------
__device__ __forceinline__ void transpose_body(const float* __restrict__ in,
                                               u16* __restrict__ out,
                                               int K, int N, int kb, int nb,
                                               int t, u16 (*tl)[66]) {
#pragma unroll
  for (int it = 0; it < 16; ++it) {
    int n_l = t & 63, k_l = it * 4 + (t >> 6);
    tl[k_l][n_l] = f2bf(in[(size_t)(kb + k_l) * N + nb + n_l]);
  }
  __syncthreads();
#pragma unroll
  for (int it = 0; it < 16; ++it) {
    int k_l = t & 63, n_l = it * 4 + (t >> 6);
    out[(size_t)(nb + n_l) * K + kb + k_l] = tl[k_l][n_l];
  }
}

__global__ __launch_bounds__(256) void k_prep(
    const float* __restrict__ qkv_w, u16* __restrict__ qkv_wT,
    const float* __restrict__ proj_w, u16* __restrict__ proj_wT,
    const float* __restrict__ ffn_w1, u16* __restrict__ w1T,
    const float* __restrict__ ffn_w2, u16* __restrict__ w2T,
    const float* __restrict__ table, const int* __restrict__ rel,
    u16* __restrict__ biasP,
    const float* __restrict__ x, const float* __restrict__ n1w,
    const float* __restrict__ n1b, u16* __restrict__ x1) {
  __shared__ __align__(16) u16 smem[CH * 68];   // 34816 B (ln1 tile / transpose tl)
  __shared__ float red_s[4][64], red_q[4][64], mu_s[64], rs_s[64];
  const int t = threadIdx.x;
  const int bx = blockIdx.x;

  if (bx < 192) {
    u16 (*tl)[66] = (u16(*)[66])smem;
    if (bx < 48) {        // qkv_w: 256x768, grid 4x12
      transpose_body(qkv_w, qkv_wT, 256, 768, (bx & 3) * 64, (bx >> 2) * 64, t, tl);
    } else if (bx < 64) { // proj_w: 256x256, grid 4x4
      int b = bx - 48;
      transpose_body(proj_w, proj_wT, 256, 256, (b & 3) * 64, (b >> 2) * 64, t, tl);
    } else if (bx < 128) { // ffn_w1: 256x1024, grid 4x16
      int b = bx - 64;
      transpose_body(ffn_w1, w1T, 256, 1024, (b & 3) * 64, (b >> 2) * 64, t, tl);
    } else {               // ffn_w2: 1024x256, grid 16x4
      int b = bx - 128;
      transpose_body(ffn_w2, w2T, 1024, 256, (b & 15) * 64, (b >> 4) * 64, t, tl);
    }
    return;
  }
  if (bx < 448) {
    // bias gather, b128-packed layout:
    //   biasP[h][jt][i][slot], slot(j') = ((j'>>2)&3)*8 + (j'>>4)*4 + (j'&3)
    const int b = bx - 192;
    const int jt = b & 31, isl = b >> 5;
    const int jp = t & 31, io = t >> 5;
    const int slot = ((jp >> 2) & 3) * 8 + (jp >> 4) * 4 + (jp & 3);
    for (int ib = isl * 128; ib < isl * 128 + 128; ib += 8) {
      int i = ib + io;
      int idx = rel[(size_t)i * NT + jt * 32 + jp];
#pragma unroll
      for (int h = 0; h < NH; ++h) {
        biasP[(((size_t)h * 32 + jt) * 1024 + i) * 32 + slot] =
            f2bf(table[(size_t)idx * NH + h] * LOG2E);
      }
    }
    return;
  }
  // LN1 fused with (B,C,n) -> (B,n,C) transpose + fp32->bf16
  {
    const int b = bx - 448;
    const int bb = b >> 4, pb = b & 15;
    const int pos0 = pb * 64;
    u16 (*tile)[68] = (u16(*)[68])smem;
#pragma unroll
    for (int it = 0; it < 16; ++it) {
      int c = it * 16 + (t >> 4), p4 = (t & 15) * 4;
      F4 v = *(const F4*)(x + ((size_t)bb * CH + c) * NT + pos0 + p4);
      US4 o; o.x = f2bf(v.x); o.y = f2bf(v.y); o.z = f2bf(v.z); o.w = f2bf(v.w);
      *(US4*)&tile[c][p4] = o;
    }
    __syncthreads();
    {
      int pos = t & 63, g = t >> 6;
      float s = 0.f, q = 0.f;
#pragma unroll 8
      for (int cc = 0; cc < 64; ++cc) {
        float v = bf2f(tile[g * 64 + cc][pos]);
        s += v; q += v * v;
      }
      red_s[g][pos] = s; red_q[g][pos] = q;
    }
    __syncthreads();
    if (t < 64) {
      float s = red_s[0][t] + red_s[1][t] + red_s[2][t] + red_s[3][t];
      float q = red_q[0][t] + red_q[1][t] + red_q[2][t] + red_q[3][t];
      float mu = s * (1.f / CH);
      float var = q * (1.f / CH) - mu * mu;
      mu_s[t] = mu;
      rs_s[t] = rsqrtf(fmaxf(var, 0.f) + LN_EPS);
    }
    __syncthreads();
    {
      const int c = t;
      const float wv = n1w[c], bv = n1b[c];
      for (int pos = 0; pos < 64; ++pos) {
        float v = (bf2f(tile[c][pos]) - mu_s[pos]) * rs_s[pos] * wv + bv;
        x1[((size_t)bb * NT + pos0 + pos) * CH + c] = f2bf(v);
      }
    }
  }
}

// ---------------------------------------------------------------------------
// m97-style LDS-staged GEMM core: 128x128 block tile, BK=32, 4 waves x 64x64.
// ---------------------------------------------------------------------------
template <int K>
__device__ __forceinline__ void gemm128(const u16* __restrict__ A,
                                        const u16* __restrict__ Bt,
                                        int r0, int c0, int tid,
                                        u16* lA, u16* lB,
                                        f32x4 acc[4][4]) {
  const int wave = tid >> 6, lane = tid & 63;
  const int wm = (wave >> 1) * 64, wn = (wave & 1) * 64;
  const int l16 = lane & 15, quad = lane >> 4;
  const int srow = lane >> 2;
  const int scol = (lane & 3) * 8;
  const u16* gA0 = A + (size_t)(r0 + wave * 16 + srow) * K + scol;
  const u16* gA1 = A + (size_t)(r0 + wave * 16 + 64 + srow) * K + scol;
  const u16* gB0 = Bt + (size_t)(c0 + wave * 16 + srow) * K + scol;
  const u16* gB1 = Bt + (size_t)(c0 + wave * 16 + 64 + srow) * K + scol;
  u16* lA0 = lA + (wave * 16) * 32;
  u16* lA1 = lA + (wave * 16 + 64) * 32;
  u16* lB0 = lB + (wave * 16) * 32;
  u16* lB1 = lB + (wave * 16 + 64) * 32;
  for (int k0 = 0; k0 < K; k0 += 32) {
    __syncthreads();
    llds16(gA0 + k0, lA0);
    llds16(gA1 + k0, lA1);
    llds16(gB0 + k0, lB0);
    llds16(gB1 + k0, lB1);
    __syncthreads();
    short8 af[4], bf[4];
#pragma unroll
    for (int i = 0; i < 4; ++i)
      af[i] = *(const short8*)&lA[(wm + i * 16 + l16) * 32 + quad * 8];
#pragma unroll
    for (int j = 0; j < 4; ++j)
      bf[j] = *(const short8*)&lB[(wn + j * 16 + l16) * 32 + quad * 8];
#pragma unroll
    for (int i = 0; i < 4; ++i)
#pragma unroll
      for (int j = 0; j < 4; ++j)
        acc[i][j] = MFMA(af[i], bf[j], acc[i][j]);
  }
}

#define GEMM_PROLOGUE(KVAL, APTR, BPTR)                                  \
  __shared__ __align__(16) u16 lA[128 * 32];                             \
  __shared__ __align__(16) u16 lB[128 * 32];                             \
  const int tid = threadIdx.x;                                           \
  const int wave = tid >> 6, lane = tid & 63;                            \
  const int wm = (wave >> 1) * 64, wn = (wave & 1) * 64;                 \
  const int l16 = lane & 15, quad = lane >> 4;                           \
  const int r0 = blockIdx.x * 128, c0 = blockIdx.y * 128;                \
  f32x4 acc[4][4];                                                       \
  _Pragma("unroll") for (int i = 0; i < 4; ++i)                          \
  _Pragma("unroll") for (int j = 0; j < 4; ++j) acc[i][j] = 0.f;         \
  gemm128<KVAL>(APTR, BPTR, r0, c0, tid, lA, lB, acc);

// ---------------------------------------------------------------------------
// 128x64-tile GEMM core (acc[2][4], LDS 12.3 KB -> ~5 blocks/CU) for the
// N=256 GEMMs (proj, ffn2). 4 waves each cover 32 rows x 64 cols.
// ---------------------------------------------------------------------------
template <int K>
__device__ __forceinline__ void gemm128x64(const u16* __restrict__ A,
                                           const u16* __restrict__ Bt,
                                           int r0, int c0, int tid,
                                           u16* lA, u16* lB,
                                           f32x4 acc[2][4]) {
  const int wave = tid >> 6, lane = tid & 63;
  const int wm = wave * 32;
  const int l16 = lane & 15, quad = lane >> 4;
  const int srow = lane >> 2;
  const int scol = (lane & 3) * 8;
  const u16* gA0 = A + (size_t)(r0 + wm + srow) * K + scol;
  const u16* gA1 = A + (size_t)(r0 + wm + 16 + srow) * K + scol;
  const u16* gB0 = Bt + (size_t)(c0 + wave * 16 + srow) * K + scol;
  u16* lA0 = lA + (size_t)wm * 32;
  u16* lA1 = lA + (size_t)(wm + 16) * 32;
  u16* lB0 = lB + (size_t)(wave * 16) * 32;
  for (int k0 = 0; k0 < K; k0 += 32) {
    __syncthreads();
    llds16(gA0 + k0, lA0);
    llds16(gA1 + k0, lA1);
    llds16(gB0 + k0, lB0);
    __syncthreads();
    short8 af[2], bf[4];
#pragma unroll
    for (int i = 0; i < 2; ++i)
      af[i] = *(const short8*)&lA[(wm + i * 16 + l16) * 32 + quad * 8];
#pragma unroll
    for (int j = 0; j < 4; ++j)
      bf[j] = *(const short8*)&lB[(j * 16 + l16) * 32 + quad * 8];
#pragma unroll
    for (int i = 0; i < 2; ++i)
#pragma unroll
      for (int j = 0; j < 4; ++j)
        acc[i][j] = MFMA(af[i], bf[j], acc[i][j]);
  }
}

#define GEMM_PROLOGUE64(KVAL, APTR, BPTR)                                \
  __shared__ __align__(16) u16 lA[128 * 32];                             \
  __shared__ __align__(16) u16 lB[64 * 32];                              \
  const int tid = threadIdx.x;                                           \
  const int wave = tid >> 6, lane = tid & 63;                            \
  const int wm = wave * 32;                                              \
  const int l16 = lane & 15, quad = lane >> 4;                           \
  const int r0 = blockIdx.x * 128, c0 = blockIdx.y * 64;                 \
  f32x4 acc[2][4];                                                       \
  _Pragma("unroll") for (int i = 0; i < 2; ++i)                          \
  _Pragma("unroll") for (int j = 0; j < 4; ++j) acc[i][j] = 0.f;         \
  gemm128x64<KVAL>(APTR, BPTR, r0, c0, tid, lA, lB, acc);

// QKV: x1(16384x256) @ qkv_wT(768x256)^T -> q (scaled), k, vT (B,H,d,n)
__global__ __launch_bounds__(256) void k_gemm_qkv(const u16* __restrict__ x1,
                                                  const u16* __restrict__ wT,
                                                  u16* __restrict__ q,
                                                  u16* __restrict__ k,
                                                  u16* __restrict__ vT) {
  GEMM_PROLOGUE(CH, x1, wT)
#pragma unroll
  for (int j = 0; j < 4; ++j) {
    int col = c0 + wn + j * 16 + l16;
    int which = col >> 8, rem = col & 255, h = rem >> 5, dd = rem & 31;
#pragma unroll
    for (int i = 0; i < 4; ++i) {
      int row0 = r0 + wm + i * 16 + quad * 4;
      int bb = row0 >> 10, pos = row0 & 1023;
      if (which == 2) {
        US4 o;
        o.x = f2bf(acc[i][j][0]); o.y = f2bf(acc[i][j][1]);
        o.z = f2bf(acc[i][j][2]); o.w = f2bf(acc[i][j][3]);
        *(US4*)(vT + (((size_t)bb * NH + h) * DH + dd) * NT + pos) = o;
      } else {
        u16* dst = (which == 0) ? q : k;
        float mul = (which == 0) ? QSCALE : 1.0f;
#pragma unroll
        for (int r = 0; r < 4; ++r)
          dst[(((size_t)bb * NH + h) * NT + pos + r) * DH + dd] =
              f2bf(acc[i][j][r] * mul);
      }
    }
  }
}

// PROJ (128x64 tiles): ao @ proj_wT + proj_b + x^T -> x3 (B,n,C) bf16
__global__ __launch_bounds__(256) void k_gemm_proj(const u16* __restrict__ ao,
                                                   const u16* __restrict__ wT,
                                                   const float* __restrict__ pb,
                                                   const float* __restrict__ x,
                                                   u16* __restrict__ x3) {
  GEMM_PROLOGUE64(CH, ao, wT)
#pragma unroll
  for (int j = 0; j < 4; ++j) {
    int col = c0 + j * 16 + l16;
    float bias = pb[col];
#pragma unroll
    for (int i = 0; i < 2; ++i) {
      int row0 = r0 + wm + i * 16 + quad * 4;
      int bb = row0 >> 10, pos = row0 & 1023;
#pragma unroll
      for (int r = 0; r < 4; ++r) {
        float val = acc[i][j][r] + bias + x[((size_t)bb * CH + col) * NT + pos + r];
        x3[(size_t)(row0 + r) * CH + col] = f2bf(val);
      }
    }
  }
}

// FFN1: x4ln(16384x256) @ w1T + b1, fast GELU -> ffn_h (16384x1024) bf16
__global__ __launch_bounds__(256) void k_gemm_ffn1(const u16* __restrict__ a,
                                                   const u16* __restrict__ wT,
                                                   const float* __restrict__ b1,
                                                   u16* __restrict__ hmat) {
  GEMM_PROLOGUE(CH, a, wT)
#pragma unroll
  for (int j = 0; j < 4; ++j) {
    int col = c0 + wn + j * 16 + l16;
    float bias = b1[col];
#pragma unroll
    for (int i = 0; i < 4; ++i) {
      int row0 = r0 + wm + i * 16 + quad * 4;
#pragma unroll
      for (int r = 0; r < 4; ++r) {
        float v = acc[i][j][r] + bias;
        hmat[(size_t)(row0 + r) * HID + col] = f2bf(fast_gelu(v));
      }
    }
  }
}

// FFN2 (128x64 tiles, + fused final residual & transpose): ffn_h @ w2T + b2,
// then out[b][col][pos] = x4 + x3[b][pos][col]  (fp32 out)
__global__ __launch_bounds__(256) void k_gemm_ffn2(const u16* __restrict__ a,
                                                   const u16* __restrict__ wT,
                                                   const float* __restrict__ b2,
                                                   const u16* __restrict__ x3,
                                                   float* __restrict__ out) {
  GEMM_PROLOGUE64(HID, a, wT)
#pragma unroll
  for (int j = 0; j < 4; ++j) {
    int col = c0 + j * 16 + l16;
    float bias = b2[col];
#pragma unroll
    for (int i = 0; i < 2; ++i) {
      int row0 = r0 + wm + i * 16 + quad * 4;
      int bb = row0 >> 10, pos = row0 & 1023;
      F4 o;
      float* po = &o.x;
#pragma unroll
      for (int r = 0; r < 4; ++r)
        po[r] = acc[i][j][r] + bias + bf2f(x3[(size_t)(row0 + r) * CH + col]);
      *(F4*)(out + ((size_t)bb * CH + col) * NT + pos) = o;
    }
  }
}

// ---------------------------------------------------------------------------
// Flash attention v4 (round-10 structure, measured 54.6 us): 64 q/block,
// S^T = K.Q^T, P in-register as MFMA16 A-frag, l via MFMA16(P, ones),
// ONE b128 bias load per tile. grid: 2048, block 256. LDS 37.4 KB.
// ---------------------------------------------------------------------------
__global__ __launch_bounds__(256) void k_attn(const u16* __restrict__ q,
                                              const u16* __restrict__ k,
                                              const u16* __restrict__ vT,
                                              const u16* __restrict__ biasP,
                                              u16* __restrict__ ao) {
  __shared__ u16 Ks[256][40];   // [j][d], stride 80 B
  __shared__ u16 Vt[32][264];   // [d][j], stride 528 B
  const int tid = threadIdx.x;
  const int wave = tid >> 6, lane = tid & 63;
  const int quad = lane >> 4, l16 = lane & 15;
  const int bh = blockIdx.x >> 4, qt = blockIdx.x & 15;
  const int h = bh & 7, bb = bh >> 3;
  const int i0 = qt * 64 + wave * 16;

  short8 aq = *(const short8*)(q + ((size_t)bh * NT + i0 + l16) * DH + quad * 8);
  const u16* bias_base =
      biasP + (((size_t)h * 32) * 1024 + (i0 + l16)) * 32 + quad * 8;

  short4v vones;
  vones[0] = vones[1] = vones[2] = vones[3] = (short)0x3F80;  // bf16 1.0
  f32x4 accl = 0.f;                  // l(q=quad*4+r) in every lane
  f32x4 accd0 = 0.f, accd1 = 0.f;    // O[q=quad*4+r][d=l16 / 16+l16]

  for (int chunk = 0; chunk < 4; ++chunk) {
    __syncthreads();
    const int rbase = chunk * 256;
    {
      const int srow = tid >> 3, sdd = (tid & 7) * 4;
#pragma unroll
      for (int it = 0; it < 8; ++it) {
        int rl = it * 32 + srow;
        US4 kv = *(const US4*)(k + ((size_t)bh * NT + rbase + rl) * DH + sdd);
        *(US4*)&Ks[rl][sdd] = kv;
      }
      const int j4 = (tid & 63) * 4;
#pragma unroll
      for (int it = 0; it < 8; ++it) {
        int d = it * 4 + wave;
        US4 vv = *(const US4*)(vT + ((size_t)bh * DH + d) * NT + rbase + j4);
        *(US4*)&Vt[d][j4] = vv;
      }
    }
    __syncthreads();

#pragma unroll 2
    for (int j0 = 0; j0 < 256; j0 += 32) {
      const int jt = (rbase + j0) >> 5;
      short8 be = *(const short8*)(bias_base + (size_t)jt * 32768);
      const u16* bep = (const u16*)&be;
      f32x4 cc0, cc1;
#pragma unroll
      for (int r = 0; r < 4; ++r) {
        cc0[r] = bf2f(bep[r]);
        cc1[r] = bf2f(bep[4 + r]);
      }
      short8 ak0 = *(const short8*)&Ks[j0 + l16][quad * 8];
      short8 ak1 = *(const short8*)&Ks[j0 + 16 + l16][quad * 8];
      f32x4 s0 = MFMA(ak0, aq, cc0);  // S^T[j=quad*4+r][q=l16]
      f32x4 s1 = MFMA(ak1, aq, cc1);
      float p00 = fast_exp2(s0[0]), p01 = fast_exp2(s0[1]);
      float p02 = fast_exp2(s0[2]), p03 = fast_exp2(s0[3]);
      float p10 = fast_exp2(s1[0]), p11 = fast_exp2(s1[1]);
      float p12 = fast_exp2(s1[2]), p13 = fast_exp2(s1[3]);
      union { u32 u[2]; short4v s; } pa0, pa1;
      pa0.u[0] = pack_bf16_pair(p00, p01);
      pa0.u[1] = pack_bf16_pair(p02, p03);
      pa1.u[0] = pack_bf16_pair(p10, p11);
      pa1.u[1] = pack_bf16_pair(p12, p13);
      short4v vb00 = *(const short4v*)&Vt[l16][j0 + quad * 4];
      short4v vb10 = *(const short4v*)&Vt[l16][j0 + 16 + quad * 4];
      short4v vb01 = *(const short4v*)&Vt[16 + l16][j0 + quad * 4];
      short4v vb11 = *(const short4v*)&Vt[16 + l16][j0 + 16 + quad * 4];
      accd0 = MFMA16(pa0.s, vb00, accd0);
      accd1 = MFMA16(pa0.s, vb01, accd1);
      accl  = MFMA16(pa0.s, vones, accl);
      accd0 = MFMA16(pa1.s, vb10, accd0);
      accd1 = MFMA16(pa1.s, vb11, accd1);
      accl  = MFMA16(pa1.s, vones, accl);
    }
  }
#pragma unroll
  for (int r = 0; r < 4; ++r) {
    float inv = 1.0f / accl[r];      // l for q = quad*4+r, no shuffles
    int row = i0 + quad * 4 + r;
    u16* o = ao + ((size_t)bb * NT + row) * CH + h * DH;
    o[l16]      = f2bf(accd0[r] * inv);
    o[16 + l16] = f2bf(accd1[r] * inv);
  }
}

// ---------------------------------------------------------------------------
// LN2: x3 (B,n,C) bf16 rows contiguous -> x4ln (B,n,C) bf16. One wave per row.
// ---------------------------------------------------------------------------
__global__ __launch_bounds__(256) void k_ln2(const u16* __restrict__ x3,
                                             const float* __restrict__ w,
                                             const float* __restrict__ b,
                                             u16* __restrict__ x4ln) {
  const int wave = threadIdx.x >> 6, lane = threadIdx.x & 63;
  const size_t row = (size_t)blockIdx.x * 4 + wave;
  US4 u = *(const US4*)(x3 + row * CH + lane * 4);
  float v0 = bf2f(u.x), v1 = bf2f(u.y), v2 = bf2f(u.z), v3 = bf2f(u.w);
  float s = v0 + v1 + v2 + v3;
  float qq = v0 * v0 + v1 * v1 + v2 * v2 + v3 * v3;
#pragma unroll
  for (int mask = 1; mask <= 32; mask <<= 1) {
    s += __shfl_xor(s, mask);
    qq += __shfl_xor(qq, mask);
  }
  float mu = s * (1.f / CH);
  float var = qq * (1.f / CH) - mu * mu;
  float rs = rsqrtf(fmaxf(var, 0.f) + LN_EPS);
  F4 uw = *(const F4*)(w + lane * 4);
  F4 ub = *(const F4*)(b + lane * 4);
  US4 o;
  o.x = f2bf((v0 - mu) * rs * uw.x + ub.x);
  o.y = f2bf((v1 - mu) * rs * uw.y + ub.y);
  o.z = f2bf((v2 - mu) * rs * uw.z + ub.z);
  o.w = f2bf((v3 - mu) * rs * uw.w + ub.w);
  *(US4*)(x4ln + row * CH + lane * 4) = o;
}

// ---------------------------------------------------------------------------
// Launch: 7 dispatches (was 12) -- prep phase horizontally fused.
// ---------------------------------------------------------------------------
extern "C" void kernel_launch(void* const* d_in, const int* in_sizes, int n_in,
                              void* d_out, int out_size, void* d_ws, size_t ws_size,
                              hipStream_t stream) {
  const float* x       = (const float*)d_in[0];
  const float* qkv_w   = (const float*)d_in[1];
  const float* proj_w  = (const float*)d_in[2];
  const float* proj_b  = (const float*)d_in[3];
  const float* ffn_w1  = (const float*)d_in[4];
  const float* ffn_b1  = (const float*)d_in[5];
  const float* ffn_w2  = (const float*)d_in[6];
  const float* ffn_b2  = (const float*)d_in[7];
  const float* norm1_w = (const float*)d_in[8];
  const float* norm1_b = (const float*)d_in[9];
  const float* norm2_w = (const float*)d_in[10];
  const float* norm2_b = (const float*)d_in[11];
  const float* btab    = (const float*)d_in[12];
  const int* rel       = (const int*)d_in[13];
  float* out = (float*)d_out;

  char* ws = (char*)d_ws;
  size_t off = 0;
  auto alloc = [&](size_t bytes) { char* p = ws + off; off += bytes; return p; };
  u16* qkv_wT  = (u16*)alloc((size_t)768 * 256 * 2);
  u16* proj_wT = (u16*)alloc((size_t)256 * 256 * 2);
  u16* w1T     = (u16*)alloc((size_t)1024 * 256 * 2);
  u16* w2T     = (u16*)alloc((size_t)256 * 1024 * 2);
  u16* biasP   = (u16*)alloc((size_t)NH * NT * NT * 2);   // 16.78 MB
  u16* qm      = (u16*)alloc((size_t)MROWS * CH * 2);     // 8.39 MB
  u16* km      = (u16*)alloc((size_t)MROWS * CH * 2);     // 8.39 MB
  u16* vm      = (u16*)alloc((size_t)MROWS * CH * 2);     // 8.39 MB (as vT)
  u16* bufX    = (u16*)alloc((size_t)MROWS * CH * 2);     // 8.39 MB
  u16* x3      = (u16*)alloc((size_t)MROWS * CH * 2);     // 8.39 MB
  u16* ffn_h = biasP;  // overlay (dead after attention)
  u16* x4ln  = vm;     // overlay (dead after attention)
  u16* x1 = bufX;
  u16* ao = bufX;
  (void)ws_size; (void)in_sizes; (void)n_in; (void)out_size;

  // fused prep: 4 transposes + bias gather + LN1 (mutually independent)
  k_prep<<<704, 256, 0, stream>>>(qkv_w, qkv_wT, proj_w, proj_wT,
                                  ffn_w1, w1T, ffn_w2, w2T,
                                  btab, rel, biasP,
                                  x, norm1_w, norm1_b, x1);
  k_gemm_qkv<<<dim3(MROWS / 128, 6), 256, 0, stream>>>(x1, qkv_wT, qm, km, vm);
  k_attn<<<BATCH * NH * 16, 256, 0, stream>>>(qm, km, vm, biasP, ao);
  k_gemm_proj<<<dim3(MROWS / 128, 4), 256, 0, stream>>>(ao, proj_wT, proj_b, x, x3);
  k_ln2<<<MROWS / 4, 256, 0, stream>>>(x3, norm2_w, norm2_b, x4ln);
  k_gemm_ffn1<<<dim3(MROWS / 128, 8), 256, 0, stream>>>(x4ln, w1T, ffn_b1, ffn_h);
  k_gemm_ffn2<<<dim3(MROWS / 128, 4), 256, 0, stream>>>(ffn_h, w2T, ffn_b2, x3, out);
}